// Round 10
// baseline (1142.599 us; speedup 1.0000x reference)
//
#include <hip/hip_runtime.h>
#include <hip/hip_bf16.h>
#include <cstdint>

typedef __attribute__((ext_vector_type(4))) float v4f;
typedef long i64;

#define DEVI __device__ __forceinline__

constexpr int kC  = 768;
constexpr int kHE = 12;
constexpr int kB  = 2;
constexpr int kSP = 32768;          // D*H*W = 8*64*64
constexpr int kNT = kB * kSP;       // 65536 tokens
constexpr int kC3 = 3 * kC;         // 2304
constexpr int kCF = 4 * kC;         // 3072

DEVI unsigned short f2bf(float f) {
  union { float f; unsigned u; } v; v.f = f;
  return (unsigned short)((v.u + 0x7fffu + ((v.u >> 16) & 1u)) >> 16);
}
// sigmoid-GELU: |err| ~1e-2 relative; h path is behind RMS-norm * 1e-6 gamma.
DEVI float gelu_fast(float v) { return v / (1.f + __expf(-1.702f * v)); }
DEVI unsigned char f2fp8(float f) {
  return (unsigned char)(__builtin_amdgcn_cvt_pk_fp8_f32(f, f, 0, false) & 0xff);
}
DEVI unsigned pk4fp8(float a, float b, float c, float d) {
  int w = __builtin_amdgcn_cvt_pk_fp8_f32(a, b, 0, false);
  w = __builtin_amdgcn_cvt_pk_fp8_f32(c, d, w, true);
  return (unsigned)w;
}
template<int SEL>
DEVI float fp82f(unsigned u) {
  return __builtin_amdgcn_cvt_f32_fp8(u, SEL);
}

typedef const __attribute__((address_space(1))) unsigned int* gas_t;
typedef __attribute__((address_space(3))) unsigned int* las_t;
DEVI void gl_lds16(const void* g, void* l) {
  __builtin_amdgcn_global_load_lds((gas_t)(uintptr_t)g, (las_t)(uintptr_t)l, 16, 0, 0);
}

#define G_BAR()  __builtin_amdgcn_s_barrier()
#define G_VM3()  asm volatile("s_waitcnt vmcnt(3)" ::: "memory")
#define G_VM0()  asm volatile("s_waitcnt vmcnt(0)" ::: "memory")

// --- fused: RMS stats (atomic) + fp8 convert + transpose x -> y8 [t][c] -----
__global__ __launch_bounds__(256) void k_rms_t(const float* __restrict__ x,
    unsigned char* __restrict__ y8, float* __restrict__ stats1) {
  __shared__ unsigned char lt[64][272];
  __shared__ float pred[256];
  int sp0 = blockIdx.x * 256, c0 = blockIdx.y * 64, b_ = blockIdx.z;
  int tid = threadIdx.x;
  int cl = tid & 63, qq = tid >> 6;       // channel, quarter
  const float4* xrow = (const float4*)(x + ((size_t)(b_ * kC + c0 + cl) << 15) + sp0);
  float s = 0.f;
  #pragma unroll
  for (int j = 0; j < 16; j++) {
    float4 v = xrow[qq * 16 + j];
    s += v.x * v.x + v.y * v.y + v.z * v.z + v.w * v.w;
    *(unsigned*)&lt[cl][(qq * 16 + j) * 4] = pk4fp8(v.x, v.y, v.z, v.w);
  }
  pred[tid] = s;
  __syncthreads();
  if (tid < 64) {
    float t = pred[tid] + pred[tid + 64] + pred[tid + 128] + pred[tid + 192];
    atomicAdd(&stats1[b_ * kC + c0 + tid], t);
  }
  #pragma unroll
  for (int i = 0; i < 4; i++) {
    int idx = i * 256 + tid;
    int spl = idx >> 2, cc = idx & 3;
    unsigned char tmp[16];
    #pragma unroll
    for (int e = 0; e < 16; e++) tmp[e] = lt[cc * 16 + e][spl];
    *(uint4*)(y8 + ((size_t)(b_ * kSP + sp0 + spl)) * kC + c0 + cc * 16) = *(uint4*)tmp;
  }
}

// ---- fc1/fc2 weights -> fp8 x16 ---------------------------------------------
__global__ __launch_bounds__(256) void k_cvt_w12(
    const float* __restrict__ a, int na4, const float* __restrict__ b, int nb4,
    unsigned char* oa, unsigned char* ob) {
  int i = blockIdx.x * 256 + threadIdx.x;
  const float* src; unsigned char* dst; int j = i;
  if (j < na4) { src = a; dst = oa; }
  else { j -= na4; if (j >= nb4) return; src = b; dst = ob; }
  float4 v = ((const float4*)src)[j];
  ((unsigned*)dst)[j] = pk4fp8(v.x * 16.f, v.y * 16.f, v.z * 16.f, v.w * 16.f);
}

// ---- w8[b][o][c] = fp8(src[o][c] * sc[b*kC+c] * 16) -------------------------
__global__ __launch_bounds__(256) void k_cvt_wscale(const float* __restrict__ src,
    const float* __restrict__ sc, unsigned char* __restrict__ dst, int rows) {
  int n4 = rows * kC / 4;
  int i = blockIdx.x * 256 + threadIdx.x;
  if (i >= 2 * n4) return;
  int b_ = i / n4;
  int j = i - b_ * n4;
  int c4 = (j * 4) % kC;
  float4 v = ((const float4*)src)[j];
  float4 s = *(const float4*)&sc[b_ * kC + c4];
  ((unsigned*)dst)[i] = pk4fp8(v.x * s.x * 16.f, v.y * s.y * 16.f,
                               v.z * s.z * 16.f, v.w * s.w * 16.f);
}

// ---------------- axial attention (fp8 qkv planes, fp8 O) --------------------
// qkv layout: [s(q,k,v)][he][token][64]  -> every 64B line = one token slice
// MODE 0: o = val ; MODE 1: o += val ; MODE 2: o += val + fused col-sumsq stats
template<int AXIS, int MODE>
__global__ __launch_bounds__(256) void k_attn(const unsigned char* __restrict__ qkv,
                                              unsigned char* __restrict__ o,
                                              float* __restrict__ stats) {
  __shared__ unsigned char qs[64][72], ks[64][72], vt[64][72], ps[64][72];
  __shared__ float sred[4][64];
  int he = blockIdx.y, g = blockIdx.x;
  int base;
  if (AXIS == 0)      base = g * 64;
  else if (AXIS == 1) base = (g >> 6) * 4096 + (g & 63);
  else                base = (g >> 9) * 32768 + ((g >> 3) & 63) * 64 + (g & 7) * 8;
  auto token = [&](int r) -> int {
    if (AXIS == 0)      return base + r;
    else if (AXIS == 1) return base + r * 64;
    else                return base + (r & 7) * 4096 + (r >> 3);
  };
  const unsigned char* qp = qkv + (size_t)he * kNT * 64;
  const unsigned char* kp = qkv + (size_t)(kHE + he) * kNT * 64;
  const unsigned char* vp = qkv + (size_t)(2 * kHE + he) * kNT * 64;
  int tid = threadIdx.x;
  #pragma unroll
  for (int it = 0; it < 2; it++) {
    int idx = it * 256 + tid;
    int row = idx >> 3, ch = idx & 7;
    size_t to = (size_t)token(row) * 64 + ch * 8;
    uint2 qv = *(const uint2*)(qp + to);
    uint2 kv = *(const uint2*)(kp + to);
    uint2 vv = *(const uint2*)(vp + to);
    *(uint2*)&qs[row][ch * 8] = qv;
    *(uint2*)&ks[row][ch * 8] = kv;
    const unsigned char* pe = (const unsigned char*)&vv;
    #pragma unroll
    for (int e = 0; e < 8; e++) vt[ch * 8 + e][row] = pe[e];
  }
  __syncthreads();
  int lane = tid & 63, wid = tid >> 6;
  int l15 = lane & 15, lq = lane >> 4;
  int r0 = wid * 16;
  v4f sacc[4];
  #pragma unroll
  for (int n = 0; n < 4; n++) sacc[n] = 0.f;
  i64 aq[2];
  #pragma unroll
  for (int kk = 0; kk < 2; kk++) aq[kk] = *(const i64*)&qs[r0 + l15][kk * 32 + lq * 8];
  #pragma unroll
  for (int n = 0; n < 4; n++) {
    #pragma unroll
    for (int kk = 0; kk < 2; kk++) {
      i64 bk = *(const i64*)&ks[n * 16 + l15][kk * 32 + lq * 8];
      sacc[n] = __builtin_amdgcn_mfma_f32_16x16x32_fp8_fp8(aq[kk], bk, sacc[n], 0, 0, 0);
    }
  }
  float p[4][4];
  #pragma unroll
  for (int r = 0; r < 4; r++) {
    float m = -1e30f;
    #pragma unroll
    for (int n = 0; n < 4; n++) {
      float v = sacc[n][r] * 0.125f;
      if (AXIS == 2) {
        int i_ = r0 + lq * 4 + r, j_ = n * 16 + l15;
        if ((i_ >> 3) != (j_ >> 3)) v = -1e30f;
      }
      p[n][r] = v; m = fmaxf(m, v);
    }
    #pragma unroll
    for (int xm = 1; xm < 16; xm <<= 1) m = fmaxf(m, __shfl_xor(m, xm));
    float ssum = 0.f;
    #pragma unroll
    for (int n = 0; n < 4; n++) { float e = __expf(p[n][r] - m); p[n][r] = e; ssum += e; }
    #pragma unroll
    for (int xm = 1; xm < 16; xm <<= 1) ssum += __shfl_xor(ssum, xm);
    float inv = 1.f / ssum;
    #pragma unroll
    for (int n = 0; n < 4; n++) p[n][r] *= inv;
  }
  #pragma unroll
  for (int n = 0; n < 4; n++)
    #pragma unroll
    for (int r = 0; r < 4; r++)
      ps[r0 + lq * 4 + r][n * 16 + l15] = f2fp8(p[n][r]);
  __syncthreads();
  v4f oacc[4];
  #pragma unroll
  for (int n = 0; n < 4; n++) oacc[n] = 0.f;
  i64 pa[2];
  #pragma unroll
  for (int kk = 0; kk < 2; kk++) pa[kk] = *(const i64*)&ps[r0 + l15][kk * 32 + lq * 8];
  #pragma unroll
  for (int n = 0; n < 4; n++) {
    #pragma unroll
    for (int kk = 0; kk < 2; kk++) {
      i64 vb = *(const i64*)&vt[n * 16 + l15][kk * 32 + lq * 8];
      oacc[n] = __builtin_amdgcn_mfma_f32_16x16x32_fp8_fp8(pa[kk], vb, oacc[n], 0, 0, 0);
    }
  }
  float csum[4];
  #pragma unroll
  for (int n = 0; n < 4; n++) {
    csum[n] = 0.f;
    #pragma unroll
    for (int r = 0; r < 4; r++) {
      int i_ = r0 + lq * 4 + r;
      size_t oa = (size_t)token(i_) * kC + he * 64 + n * 16 + l15;
      float val = oacc[n][r];
      if (MODE >= 1) val += fp82f<0>((unsigned)o[oa]);
      o[oa] = f2fp8(val);
      if (MODE == 2) csum[n] += val * val;
    }
  }
  if (MODE == 2) {
    #pragma unroll
    for (int n = 0; n < 4; n++) {
      csum[n] += __shfl_xor(csum[n], 16);
      csum[n] += __shfl_xor(csum[n], 32);
    }
    if (lq == 0) {
      #pragma unroll
      for (int n = 0; n < 4; n++) sred[wid][n * 16 + l15] = csum[n];
    }
    __syncthreads();
    if (tid < 64) {
      float s = sred[0][tid] + sred[1][tid] + sred[2][tid] + sred[3][tid];
      int b_ = token(0) >> 15;
      atomicAdd(&stats[b_ * kC + he * 64 + tid], s);
    }
  }
}

// ---- fp8 GEMM 256x128, 8 waves (4m x 2n), BK=64, 3-buf, 1 barrier/K-tile ---
// 72 KiB LDS + acc[4][4] -> 2 blocks/CU for cross-block overlap.
// D[M][N] = A[M][K] * B^T[N][K]; weights pre-scaled x16 -> acc * (1/16)
// EPI 1: +bias, fused q/k LayerNorm -> fp8 qkv PLANES [s][he][t][64]
// EPI 2: +bias -> fp8 channel-major (z, raw attn projection)
// EPI 3: gelu(+bias) -> fp8 token-major (fc1)
// EPI 4: +bias -> fp8 channel-major + atomic sumsq stats (fc2)
template<int EPI>
__global__ __launch_bounds__(512, 4) void k_gemm8(
    const unsigned char* __restrict__ A, const unsigned char* __restrict__ Bt,
    const float* __restrict__ bias, int K, int tiles_m, int tiles_n, int swz,
    void* __restrict__ outp, int ld_out, i64 abst,
    float* __restrict__ stats, int t0,
    const float* __restrict__ ln0w, const float* __restrict__ ln0b,
    const float* __restrict__ ln1w, const float* __restrict__ ln1b) {
  __shared__ __align__(16) unsigned char lds[73728];
  constexpr float S = 1.f / 16.f;
  int cpx = gridDim.x >> 3;
  int bid = (blockIdx.x & 7) * cpx + (blockIdx.x >> 3);
  int group = swz * tiles_m;
  int gidx = bid / group, rem = bid - gidx * group;
  int n0t = gidx * swz;
  int sw = min(swz, tiles_n - n0t);
  int tn = n0t + rem % sw;
  int tm = rem / sw;
  int m0 = tm * 256, n0 = tn * 128;
  const unsigned char* Ab = A + (size_t)(n0 >> 15) * abst + (size_t)m0 * K;
  const unsigned char* Bb = Bt + (size_t)n0 * K;
  int tid = threadIdx.x;
  int lane = tid & 63;
  int l15 = lane & 15, lq = lane >> 4;
  int wid = tid >> 6, wm = wid >> 1, wn = wid & 1;
  int xr8 = l15 & 6;
  int aoff0 = ((0 + lq) ^ xr8) * 8;
  int aoff1 = ((4 + lq) ^ xr8) * 8;
  int arow = (wm * 64 + l15) * 64;
  int brow = (wn * 64 + l15) * 64;
  int grow = tid >> 2;
  int gch  = (tid & 3) ^ ((grow >> 1) & 3);
  size_t stago = (size_t)grow * K + gch * 16;
  int ldst = tid * 16;

  v4f acc[4][4];
  #pragma unroll
  for (int m = 0; m < 4; m++)
    #pragma unroll
    for (int n = 0; n < 4; n++) acc[m][n] = 0.f;

  auto stage = [&](int kt, int buf) {
    const unsigned char* ga = Ab + stago + kt * 64;
    unsigned char* la = lds + buf * 16384 + ldst;
    gl_lds16(ga, la);
    gl_lds16(ga + (size_t)128 * K, la + 8192);
    gl_lds16(Bb + stago + kt * 64, lds + 49152 + buf * 8192 + ldst);
  };

  int NT = K >> 6;
  stage(0, 0);
  stage(min(1, NT - 1), 1);
  G_VM3(); G_BAR();
  int cur = 0;
  for (int t = 0; t < NT; t++) {
    int kt2 = (t + 2 < NT) ? t + 2 : NT - 1;
    int nxt = cur + 2; if (nxt >= 3) nxt -= 3;
    stage(kt2, nxt);
    const unsigned char* ab = lds + cur * 16384 + arow;
    const unsigned char* bb = lds + 49152 + cur * 8192 + brow;
    i64 a0[4], a1[4], b0[4], b1[4];
    #pragma unroll
    for (int m = 0; m < 4; m++) {
      a0[m] = *(const i64*)(ab + m * 1024 + aoff0);
      a1[m] = *(const i64*)(ab + m * 1024 + aoff1);
    }
    #pragma unroll
    for (int n = 0; n < 4; n++) {
      b0[n] = *(const i64*)(bb + n * 1024 + aoff0);
      b1[n] = *(const i64*)(bb + n * 1024 + aoff1);
    }
    __builtin_amdgcn_s_setprio(1);
    #pragma unroll
    for (int m = 0; m < 4; m++)
      #pragma unroll
      for (int n = 0; n < 4; n++)
        acc[m][n] = __builtin_amdgcn_mfma_f32_16x16x32_fp8_fp8(a0[m], b0[n], acc[m][n], 0, 0, 0);
    #pragma unroll
    for (int m = 0; m < 4; m++)
      #pragma unroll
      for (int n = 0; n < 4; n++)
        acc[m][n] = __builtin_amdgcn_mfma_f32_16x16x32_fp8_fp8(a1[m], b1[n], acc[m][n], 0, 0, 0);
    __builtin_amdgcn_s_setprio(0);
    G_VM3(); G_BAR();
    cur++; if (cur == 3) cur = 0;
  }
  G_VM0();

  int chb0 = m0 + wm * 64;
  int tb0  = n0 + wn * 64;
  if constexpr (EPI == 1) {
    // fused q/k LayerNorm (wave's 64 channels = one (he,s) group) -> plane write
    unsigned char* out8 = (unsigned char*)outp;
    int he = chb0 / 192;
    int s = (chb0 >> 6) % 3;
    unsigned char* plane = out8 + (size_t)(s * kHE + he) * kNT * 64;
    #pragma unroll
    for (int n = 0; n < 4; n++) {
      int t = tb0 + n * 16 + l15;
      unsigned char* orow = plane + (size_t)t * 64;
      float vv[4][4];
      float s1 = 0.f, s2 = 0.f;
      #pragma unroll
      for (int m4 = 0; m4 < 4; m4++) {
        float4 bb = *(const float4*)&bias[chb0 + m4 * 16 + lq * 4];
        float v0 = acc[m4][n][0] * S + bb.x, v1 = acc[m4][n][1] * S + bb.y;
        float v2 = acc[m4][n][2] * S + bb.z, v3 = acc[m4][n][3] * S + bb.w;
        vv[m4][0] = v0; vv[m4][1] = v1; vv[m4][2] = v2; vv[m4][3] = v3;
        s1 += v0 + v1 + v2 + v3;
        s2 += v0 * v0 + v1 * v1 + v2 * v2 + v3 * v3;
      }
      s1 += __shfl_xor(s1, 16); s1 += __shfl_xor(s1, 32);
      s2 += __shfl_xor(s2, 16); s2 += __shfl_xor(s2, 32);
      if (s < 2) {
        const float* wp = s ? ln1w : ln0w;
        const float* bp = s ? ln1b : ln0b;
        float mu = s1 * (1.f / 64.f);
        float inv = rsqrtf(s2 * (1.f / 64.f) - mu * mu + 1e-5f);
        #pragma unroll
        for (int m4 = 0; m4 < 4; m4++) {
          int j = m4 * 16 + lq * 4;
          float4 w4 = *(const float4*)&wp[j];
          float4 b4 = *(const float4*)&bp[j];
          vv[m4][0] = (vv[m4][0] - mu) * inv * w4.x + b4.x;
          vv[m4][1] = (vv[m4][1] - mu) * inv * w4.y + b4.y;
          vv[m4][2] = (vv[m4][2] - mu) * inv * w4.z + b4.z;
          vv[m4][3] = (vv[m4][3] - mu) * inv * w4.w + b4.w;
        }
      }
      unsigned wds[4];
      #pragma unroll
      for (int m4 = 0; m4 < 4; m4++)
        wds[m4] = pk4fp8(vv[m4][0], vv[m4][1], vv[m4][2], vv[m4][3]);
      #pragma unroll
      for (int m4 = 0; m4 < 4; m4++)
        *(unsigned*)(orow + m4 * 16 + lq * 4) = wds[m4];
    }
  } else if constexpr (EPI == 2) {
    unsigned char* out8 = (unsigned char*)outp;
    int b_ = tb0 >> 15;
    #pragma unroll
    for (int m = 0; m < 4; m++) {
      int chb = chb0 + m * 16 + lq * 4;
      float4 bb = *(const float4*)&bias[chb];
      #pragma unroll
      for (int n = 0; n < 4; n++) {
        int t = tb0 + n * 16 + l15;
        int sp = t & (kSP - 1);
        size_t cmb = ((size_t)(b_ * kC + chb) << 15) + sp;
        out8[cmb]           = f2fp8(acc[m][n][0] * S + bb.x);
        out8[cmb + kSP]     = f2fp8(acc[m][n][1] * S + bb.y);
        out8[cmb + 2 * kSP] = f2fp8(acc[m][n][2] * S + bb.z);
        out8[cmb + 3 * kSP] = f2fp8(acc[m][n][3] * S + bb.w);
      }
    }
  } else if constexpr (EPI == 3) {
    // n-outer / m-inner, compute-then-store: the 4 stores completing each
    // 64B output line issue back-to-back (avoids partial-sector eviction).
    unsigned char* out8 = (unsigned char*)outp;
    #pragma unroll
    for (int n = 0; n < 4; n++) {
      int t = tb0 + n * 16 + l15;
      unsigned char* orow = out8 + (size_t)t * ld_out;
      unsigned wds[4];
      #pragma unroll
      for (int m = 0; m < 4; m++) {
        int chb = chb0 + m * 16 + lq * 4;
        float4 bb = *(const float4*)&bias[chb];
        wds[m] = pk4fp8(gelu_fast(acc[m][n][0] * S + bb.x),
                        gelu_fast(acc[m][n][1] * S + bb.y),
                        gelu_fast(acc[m][n][2] * S + bb.z),
                        gelu_fast(acc[m][n][3] * S + bb.w));
      }
      #pragma unroll
      for (int m = 0; m < 4; m++)
        *(unsigned*)(orow + chb0 + m * 16 + lq * 4) = wds[m];
    }
  } else {  // EPI == 4
    unsigned char* out8 = (unsigned char*)outp;
    int b_ = (t0 + tb0) >> 15;
    #pragma unroll
    for (int m = 0; m < 4; m++) {
      int chb = chb0 + m * 16 + lq * 4;
      float4 bb = *(const float4*)&bias[chb];
      float q0 = 0.f, q1 = 0.f, q2 = 0.f, q3 = 0.f;
      #pragma unroll
      for (int n = 0; n < 4; n++) {
        int tg = t0 + tb0 + n * 16 + l15;
        int sp = tg & (kSP - 1);
        size_t cmb = ((size_t)(b_ * kC + chb) << 15) + sp;
        float v0 = acc[m][n][0] * S + bb.x, v1 = acc[m][n][1] * S + bb.y;
        float v2 = acc[m][n][2] * S + bb.z, v3 = acc[m][n][3] * S + bb.w;
        out8[cmb] = f2fp8(v0); out8[cmb + kSP] = f2fp8(v1);
        out8[cmb + 2 * kSP] = f2fp8(v2); out8[cmb + 3 * kSP] = f2fp8(v3);
        q0 += v0 * v0; q1 += v1 * v1; q2 += v2 * v2; q3 += v3 * v3;
      }
      #pragma unroll
      for (int xm = 1; xm < 16; xm <<= 1) {
        q0 += __shfl_xor(q0, xm); q1 += __shfl_xor(q1, xm);
        q2 += __shfl_xor(q2, xm); q3 += __shfl_xor(q3, xm);
      }
      if (l15 == 0) {
        atomicAdd(&stats[b_ * kC + chb], q0);
        atomicAdd(&stats[b_ * kC + chb + 1], q1);
        atomicAdd(&stats[b_ * kC + chb + 2], q2);
        atomicAdd(&stats[b_ * kC + chb + 3], q3);
      }
    }
  }
}

__global__ __launch_bounds__(256) void k_scale(const float* __restrict__ stats,
    const float* __restrict__ w, float* __restrict__ sc, float invn, float post) {
  int i = blockIdx.x * 256 + threadIdx.x;
  if (i >= kB * kC) return;
  sc[i] = post * rsqrtf(stats[i] * invn + 1e-6f) * w[i % kC];
}

// out = x + gatt*z + gmlp*s3*h   (all channel-major [b][c][sp], z/h fp8)
__global__ __launch_bounds__(256) void k_final(float* __restrict__ out,
    const float* __restrict__ x, const unsigned char* __restrict__ z8,
    const unsigned char* __restrict__ h8, const float* __restrict__ s3,
    const float* __restrict__ ga, const float* __restrict__ gm) {
  size_t e = ((size_t)blockIdx.x * 256 + threadIdx.x) * 4;
  int bc = (int)(e >> 15);
  int c = bc % kC;
  float sa = ga[c], sm = gm[c] * s3[bc];
  float4 v = *(const float4*)(x + e);
  unsigned zu = *(const unsigned*)(z8 + e);
  unsigned hu = *(const unsigned*)(h8 + e);
  v.x += sa * fp82f<0>(zu) + sm * fp82f<0>(hu);
  v.y += sa * fp82f<1>(zu) + sm * fp82f<1>(hu);
  v.z += sa * fp82f<2>(zu) + sm * fp82f<2>(hu);
  v.w += sa * fp82f<3>(zu) + sm * fp82f<3>(hu);
  *(float4*)(out + e) = v;
}

// ----------------------------------------------------------------------------
extern "C" void kernel_launch(void* const* d_in, const int* in_sizes, int n_in,
                              void* d_out, int out_size, void* d_ws, size_t ws_size,
                              hipStream_t stream) {
  (void)in_sizes; (void)n_in;
  const float* x    = (const float*)d_in[0];
  const float* n1w  = (const float*)d_in[1];
  const float* n2w  = (const float*)d_in[2];
  const float* nmw  = (const float*)d_in[3];
  const float* qkvw = (const float*)d_in[4];
  const float* qkvb = (const float*)d_in[5];
  const float* outw = (const float*)d_in[6];
  const float* outb = (const float*)d_in[7];
  const float* qnw  = (const float*)d_in[8];
  const float* qnb  = (const float*)d_in[9];
  const float* knw  = (const float*)d_in[10];
  const float* knb  = (const float*)d_in[11];
  const float* gatt = (const float*)d_in[12];
  const float* gmlp = (const float*)d_in[13];
  const float* f1w  = (const float*)d_in[14];
  const float* f1b  = (const float*)d_in[15];
  const float* f2w  = (const float*)d_in[16];
  const float* f2b  = (const float*)d_in[17];

  size_t off = 0;
  auto alloc = [&](size_t bytes) { size_t o = off; off += (bytes + 255) & ~(size_t)255; return o; };
  size_t o_wq8 = alloc((size_t)2 * kC3 * kC);      // per-batch, sc1-folded, x16
  size_t o_wo8 = alloc((size_t)2 * kC * kC);       // per-batch, sc2-folded, x16
  size_t o_w18 = alloc((size_t)kCF * kC);          // x16
  size_t o_w28 = alloc((size_t)kC * kCF);          // x16
  size_t o_s1  = alloc(kB * kC * 4);
  size_t o_s2  = alloc(kB * kC * 4);
  size_t o_s3  = alloc(kB * kC * 4);
  size_t o_st  = alloc(3 * kB * kC * 4);           // stats1 | stats_o | stats_h
  size_t o_y8  = alloc((size_t)kNT * kC);          // y8 = fp8(x^T): GEMM1 B + fc1 B
  size_t o_qk  = alloc((size_t)kNT * kC3);         // qkv8 planes -> h28 (reuse front)
  size_t o_O8  = alloc((size_t)kNT * kC);          // attention accumulator
  size_t o_z   = alloc((size_t)kNT * kC);          // z fp8 channel-major
  size_t o_hc  = alloc((size_t)kNT * kCF);         // hck fp8 (full, 201 MB)
  if (ws_size < off) {
    hipMemsetAsync(d_out, 0x7F, (size_t)out_size * 4, stream);
    return;
  }
  char* ws = (char*)d_ws;
  unsigned char* wq8 = (unsigned char*)(ws + o_wq8);
  unsigned char* wo8 = (unsigned char*)(ws + o_wo8);
  unsigned char* w18 = (unsigned char*)(ws + o_w18);
  unsigned char* w28 = (unsigned char*)(ws + o_w28);
  float* sc1 = (float*)(ws + o_s1);
  float* sc2 = (float*)(ws + o_s2);
  float* sc3 = (float*)(ws + o_s3);
  float* stats1  = (float*)(ws + o_st);
  float* stats_o = stats1 + kB * kC;
  float* stats_h = stats1 + 2 * kB * kC;
  unsigned char* y8   = (unsigned char*)(ws + o_y8);
  unsigned char* qkv8 = (unsigned char*)(ws + o_qk);
  unsigned char* h28  = (unsigned char*)(ws + o_qk);   // reuse (qkv dead after attn)
  unsigned char* O8   = (unsigned char*)(ws + o_O8);
  unsigned char* z8   = (unsigned char*)(ws + o_z);
  unsigned char* hck  = (unsigned char*)(ws + o_hc);
  float* out = (float*)d_out;

  hipMemsetAsync(ws + o_st, 0, 3 * kB * kC * 4, stream);
  k_rms_t<<<dim3(kSP / 256, kC / 64, kB), 256, 0, stream>>>(x, y8, stats1);
  k_scale<<<6, 256, 0, stream>>>(stats1, n1w, sc1, 1.f / kSP, 1.f);
  k_cvt_w12<<<(2 * kCF * kC / 4 + 255) / 256, 256, 0, stream>>>(
      f1w, kCF * kC / 4, f2w, kC * kCF / 4, w18, w28);
  k_cvt_wscale<<<(2 * kC3 * kC / 4 + 255) / 256, 256, 0, stream>>>(qkvw, sc1, wq8, kC3);
  k_gemm8<1><<<4608, 512, 0, stream>>>(wq8, y8, qkvb, kC, 9, 512, 1,
                                       qkv8, 0, (i64)kC3 * kC, nullptr, 0,
                                       qnw, qnb, knw, knb);
  k_attn<0, 0><<<dim3(1024, kHE), 256, 0, stream>>>(qkv8, O8, nullptr);
  k_attn<1, 1><<<dim3(1024, kHE), 256, 0, stream>>>(qkv8, O8, nullptr);
  k_attn<2, 2><<<dim3(1024, kHE), 256, 0, stream>>>(qkv8, O8, stats_o);
  k_scale<<<6, 256, 0, stream>>>(stats_o, n2w, sc2, 1.f / (9.f * kSP), 1.f / 3.f);
  k_cvt_wscale<<<(2 * kC * kC / 4 + 255) / 256, 256, 0, stream>>>(outw, sc2, wo8, kC);
  k_gemm8<2><<<1536, 512, 0, stream>>>(wo8, O8, outb, kC, 3, 512, 1,
                                       z8, 0, (i64)kC * kC, nullptr, 0,
                                       nullptr, nullptr, nullptr, nullptr);
  k_gemm8<3><<<6144, 512, 0, stream>>>(w18, y8, f1b, kC, 12, 512, 1,
                                       hck, kCF, 0, nullptr, 0,
                                       nullptr, nullptr, nullptr, nullptr);
  k_gemm8<4><<<1536, 512, 0, stream>>>(w28, hck, f2b, kCF, 3, 512, 1,
                                       h28, 0, 0, stats_h, 0,
                                       nullptr, nullptr, nullptr, nullptr);
  k_scale<<<6, 256, 0, stream>>>(stats_h, nmw, sc3, 1.f / kSP, 1.f);
  k_final<<<kNT * kC / 1024, 256, 0, stream>>>(out, x, z8, h28, sc3, gatt, gmlp);
}

// Round 11
// 1116.122 us; speedup vs baseline: 1.0237x; 1.0237x over previous
//
#include <hip/hip_runtime.h>
#include <hip/hip_bf16.h>
#include <cstdint>

typedef __attribute__((ext_vector_type(4))) float v4f;
typedef __attribute__((ext_vector_type(2))) long i64x2;
typedef long i64;

#define DEVI __device__ __forceinline__

constexpr int kC  = 768;
constexpr int kHE = 12;
constexpr int kB  = 2;
constexpr int kSP = 32768;          // D*H*W = 8*64*64
constexpr int kNT = kB * kSP;       // 65536 tokens
constexpr int kC3 = 3 * kC;         // 2304
constexpr int kCF = 4 * kC;         // 3072

DEVI unsigned short f2bf(float f) {
  union { float f; unsigned u; } v; v.f = f;
  return (unsigned short)((v.u + 0x7fffu + ((v.u >> 16) & 1u)) >> 16);
}
// sigmoid-GELU: |err| ~1e-2 relative; h path is behind RMS-norm * 1e-6 gamma.
DEVI float gelu_fast(float v) { return v / (1.f + __expf(-1.702f * v)); }
DEVI unsigned char f2fp8(float f) {
  return (unsigned char)(__builtin_amdgcn_cvt_pk_fp8_f32(f, f, 0, false) & 0xff);
}
DEVI unsigned pk4fp8(float a, float b, float c, float d) {
  int w = __builtin_amdgcn_cvt_pk_fp8_f32(a, b, 0, false);
  w = __builtin_amdgcn_cvt_pk_fp8_f32(c, d, w, true);
  return (unsigned)w;
}
template<int SEL>
DEVI float fp82f(unsigned u) {
  return __builtin_amdgcn_cvt_f32_fp8(u, SEL);
}

typedef const __attribute__((address_space(1))) unsigned int* gas_t;
typedef __attribute__((address_space(3))) unsigned int* las_t;
DEVI void gl_lds16(const void* g, void* l) {
  __builtin_amdgcn_global_load_lds((gas_t)(uintptr_t)g, (las_t)(uintptr_t)l, 16, 0, 0);
}

#define G_BAR()  __builtin_amdgcn_s_barrier()
#define G_VM6()  asm volatile("s_waitcnt vmcnt(6)" ::: "memory")
#define G_VM0()  asm volatile("s_waitcnt vmcnt(0)" ::: "memory")

// --- fused: RMS stats (atomic) + fp8 convert + transpose x -> y8 [t][c] -----
__global__ __launch_bounds__(256) void k_rms_t(const float* __restrict__ x,
    unsigned char* __restrict__ y8, float* __restrict__ stats1) {
  __shared__ unsigned char lt[64][272];
  __shared__ float pred[256];
  int sp0 = blockIdx.x * 256, c0 = blockIdx.y * 64, b_ = blockIdx.z;
  int tid = threadIdx.x;
  int cl = tid & 63, qq = tid >> 6;       // channel, quarter
  const float4* xrow = (const float4*)(x + ((size_t)(b_ * kC + c0 + cl) << 15) + sp0);
  float s = 0.f;
  #pragma unroll
  for (int j = 0; j < 16; j++) {
    float4 v = xrow[qq * 16 + j];
    s += v.x * v.x + v.y * v.y + v.z * v.z + v.w * v.w;
    *(unsigned*)&lt[cl][(qq * 16 + j) * 4] = pk4fp8(v.x, v.y, v.z, v.w);
  }
  pred[tid] = s;
  __syncthreads();
  if (tid < 64) {
    float t = pred[tid] + pred[tid + 64] + pred[tid + 128] + pred[tid + 192];
    atomicAdd(&stats1[b_ * kC + c0 + tid], t);
  }
  #pragma unroll
  for (int i = 0; i < 4; i++) {
    int idx = i * 256 + tid;
    int spl = idx >> 2, cc = idx & 3;
    unsigned char tmp[16];
    #pragma unroll
    for (int e = 0; e < 16; e++) tmp[e] = lt[cc * 16 + e][spl];
    *(uint4*)(y8 + ((size_t)(b_ * kSP + sp0 + spl)) * kC + c0 + cc * 16) = *(uint4*)tmp;
  }
}

// ---- fc1/fc2 weights -> fp8 x16 ---------------------------------------------
__global__ __launch_bounds__(256) void k_cvt_w12(
    const float* __restrict__ a, int na4, const float* __restrict__ b, int nb4,
    unsigned char* oa, unsigned char* ob) {
  int i = blockIdx.x * 256 + threadIdx.x;
  const float* src; unsigned char* dst; int j = i;
  if (j < na4) { src = a; dst = oa; }
  else { j -= na4; if (j >= nb4) return; src = b; dst = ob; }
  float4 v = ((const float4*)src)[j];
  ((unsigned*)dst)[j] = pk4fp8(v.x * 16.f, v.y * 16.f, v.z * 16.f, v.w * 16.f);
}

// ---- w8[b][o][c] = fp8(src[o][c] * sc[b*kC+c] * 16) -------------------------
__global__ __launch_bounds__(256) void k_cvt_wscale(const float* __restrict__ src,
    const float* __restrict__ sc, unsigned char* __restrict__ dst, int rows) {
  int n4 = rows * kC / 4;
  int i = blockIdx.x * 256 + threadIdx.x;
  if (i >= 2 * n4) return;
  int b_ = i / n4;
  int j = i - b_ * n4;
  int c4 = (j * 4) % kC;
  float4 v = ((const float4*)src)[j];
  float4 s = *(const float4*)&sc[b_ * kC + c4];
  ((unsigned*)dst)[i] = pk4fp8(v.x * s.x * 16.f, v.y * s.y * 16.f,
                               v.z * s.z * 16.f, v.w * s.w * 16.f);
}

// ---------------- axial attention (fp8 qkv planes, fp8 O) --------------------
// qkv layout: [s(q,k,v)][he][token][64]  -> every 64B line = one token slice
// MODE 0: o = val ; MODE 1: o += val ; MODE 2: o += val + fused col-sumsq stats
template<int AXIS, int MODE>
__global__ __launch_bounds__(256) void k_attn(const unsigned char* __restrict__ qkv,
                                              unsigned char* __restrict__ o,
                                              float* __restrict__ stats) {
  __shared__ unsigned char qs[64][72], ks[64][72], vt[64][72], ps[64][72];
  __shared__ float sred[4][64];
  int he = blockIdx.y, g = blockIdx.x;
  int base;
  if (AXIS == 0)      base = g * 64;
  else if (AXIS == 1) base = (g >> 6) * 4096 + (g & 63);
  else                base = (g >> 9) * 32768 + ((g >> 3) & 63) * 64 + (g & 7) * 8;
  auto token = [&](int r) -> int {
    if (AXIS == 0)      return base + r;
    else if (AXIS == 1) return base + r * 64;
    else                return base + (r & 7) * 4096 + (r >> 3);
  };
  const unsigned char* qp = qkv + (size_t)he * kNT * 64;
  const unsigned char* kp = qkv + (size_t)(kHE + he) * kNT * 64;
  const unsigned char* vp = qkv + (size_t)(2 * kHE + he) * kNT * 64;
  int tid = threadIdx.x;
  #pragma unroll
  for (int it = 0; it < 2; it++) {
    int idx = it * 256 + tid;
    int row = idx >> 3, ch = idx & 7;
    size_t to = (size_t)token(row) * 64 + ch * 8;
    uint2 qv = *(const uint2*)(qp + to);
    uint2 kv = *(const uint2*)(kp + to);
    uint2 vv = *(const uint2*)(vp + to);
    *(uint2*)&qs[row][ch * 8] = qv;
    *(uint2*)&ks[row][ch * 8] = kv;
    const unsigned char* pe = (const unsigned char*)&vv;
    #pragma unroll
    for (int e = 0; e < 8; e++) vt[ch * 8 + e][row] = pe[e];
  }
  __syncthreads();
  int lane = tid & 63, wid = tid >> 6;
  int l15 = lane & 15, lq = lane >> 4;
  int r0 = wid * 16;
  v4f sacc[4];
  #pragma unroll
  for (int n = 0; n < 4; n++) sacc[n] = 0.f;
  i64 aq[2];
  #pragma unroll
  for (int kk = 0; kk < 2; kk++) aq[kk] = *(const i64*)&qs[r0 + l15][kk * 32 + lq * 8];
  #pragma unroll
  for (int n = 0; n < 4; n++) {
    #pragma unroll
    for (int kk = 0; kk < 2; kk++) {
      i64 bk = *(const i64*)&ks[n * 16 + l15][kk * 32 + lq * 8];
      sacc[n] = __builtin_amdgcn_mfma_f32_16x16x32_fp8_fp8(aq[kk], bk, sacc[n], 0, 0, 0);
    }
  }
  float p[4][4];
  #pragma unroll
  for (int r = 0; r < 4; r++) {
    float m = -1e30f;
    #pragma unroll
    for (int n = 0; n < 4; n++) {
      float v = sacc[n][r] * 0.125f;
      if (AXIS == 2) {
        int i_ = r0 + lq * 4 + r, j_ = n * 16 + l15;
        if ((i_ >> 3) != (j_ >> 3)) v = -1e30f;
      }
      p[n][r] = v; m = fmaxf(m, v);
    }
    #pragma unroll
    for (int xm = 1; xm < 16; xm <<= 1) m = fmaxf(m, __shfl_xor(m, xm));
    float ssum = 0.f;
    #pragma unroll
    for (int n = 0; n < 4; n++) { float e = __expf(p[n][r] - m); p[n][r] = e; ssum += e; }
    #pragma unroll
    for (int xm = 1; xm < 16; xm <<= 1) ssum += __shfl_xor(ssum, xm);
    float inv = 1.f / ssum;
    #pragma unroll
    for (int n = 0; n < 4; n++) p[n][r] *= inv;
  }
  #pragma unroll
  for (int n = 0; n < 4; n++)
    #pragma unroll
    for (int r = 0; r < 4; r++)
      ps[r0 + lq * 4 + r][n * 16 + l15] = f2fp8(p[n][r]);
  __syncthreads();
  v4f oacc[4];
  #pragma unroll
  for (int n = 0; n < 4; n++) oacc[n] = 0.f;
  i64 pa[2];
  #pragma unroll
  for (int kk = 0; kk < 2; kk++) pa[kk] = *(const i64*)&ps[r0 + l15][kk * 32 + lq * 8];
  #pragma unroll
  for (int n = 0; n < 4; n++) {
    #pragma unroll
    for (int kk = 0; kk < 2; kk++) {
      i64 vb = *(const i64*)&vt[n * 16 + l15][kk * 32 + lq * 8];
      oacc[n] = __builtin_amdgcn_mfma_f32_16x16x32_fp8_fp8(pa[kk], vb, oacc[n], 0, 0, 0);
    }
  }
  float csum[4];
  #pragma unroll
  for (int n = 0; n < 4; n++) {
    csum[n] = 0.f;
    #pragma unroll
    for (int r = 0; r < 4; r++) {
      int i_ = r0 + lq * 4 + r;
      size_t oa = (size_t)token(i_) * kC + he * 64 + n * 16 + l15;
      float val = oacc[n][r];
      if (MODE >= 1) val += fp82f<0>((unsigned)o[oa]);
      o[oa] = f2fp8(val);
      if (MODE == 2) csum[n] += val * val;
    }
  }
  if (MODE == 2) {
    #pragma unroll
    for (int n = 0; n < 4; n++) {
      csum[n] += __shfl_xor(csum[n], 16);
      csum[n] += __shfl_xor(csum[n], 32);
    }
    if (lq == 0) {
      #pragma unroll
      for (int n = 0; n < 4; n++) sred[wid][n * 16 + l15] = csum[n];
    }
    __syncthreads();
    if (tid < 64) {
      float s = sred[0][tid] + sred[1][tid] + sred[2][tid] + sred[3][tid];
      int b_ = token(0) >> 15;
      atomicAdd(&stats[b_ * kC + he * 64 + tid], s);
    }
  }
}

// ---- fp8 GEMM 256x128, 4 waves, wave tile 128x64, BK=64, 3-buf -------------
// Interleaved-k ds_read_b128: MFMA0 consumes even 8B k-slots, MFMA1 odd slots
// (same permutation on A and B -> dot product unchanged). 12 b128/wave/K-tile,
// conflict-free (8 words/bank floor). 72 KiB LDS + 128-VGPR acc -> 2 blk/CU.
// EPI 1: +bias, fused q/k LayerNorm -> fp8 qkv PLANES [s][he][t][64]
// EPI 2: +bias -> fp8 channel-major (z) ; EPI 3: gelu -> fp8 token-major
// EPI 4: +bias -> fp8 channel-major + atomic sumsq stats
template<int EPI>
__global__ __launch_bounds__(256, 2) void k_gemm8(
    const unsigned char* __restrict__ A, const unsigned char* __restrict__ Bt,
    const float* __restrict__ bias, int K, int tiles_m, int tiles_n, int swz,
    void* __restrict__ outp, int ld_out, i64 abst,
    float* __restrict__ stats, int t0,
    const float* __restrict__ ln0w, const float* __restrict__ ln0b,
    const float* __restrict__ ln1w, const float* __restrict__ ln1b) {
  // per buf: A 16 KiB @0, B 8 KiB @16384 ; 3 bufs x 24 KiB = 72 KiB
  __shared__ __align__(16) unsigned char lds[73728];
  constexpr float S = 1.f / 16.f;
  int cpx = gridDim.x >> 3;
  int bid = (blockIdx.x & 7) * cpx + (blockIdx.x >> 3);
  int group = swz * tiles_m;
  int gidx = bid / group, rem = bid - gidx * group;
  int n0t = gidx * swz;
  int sw = min(swz, tiles_n - n0t);
  int tn = n0t + rem % sw;
  int tm = rem / sw;
  int m0 = tm * 256, n0 = tn * 128;
  const unsigned char* Ab = A + (size_t)(n0 >> 15) * abst + (size_t)m0 * K;
  const unsigned char* Bb = Bt + (size_t)n0 * K;
  int tid = threadIdx.x;
  int lane = tid & 63;
  int l15 = lane & 15, lq = lane >> 4;
  int wid = tid >> 6, wm = wid >> 1, wn = wid & 1;
  // 16B-chunk XOR swizzle: LDS chunk c holds global chunk c ^ ((row>>1)&3)
  int ck = (lq ^ ((l15 >> 1) & 3)) * 16;        // swizzled read chunk offset
  int arow = (wm * 128 + l15) * 64;
  int brow = (wn * 64 + l15) * 64;
  int grow = tid >> 2;                          // staging row 0..63 per pass
  int gch  = (tid & 3) ^ ((tid >> 3) & 3);      // inverse-swizzled 16B chunk
  size_t stago = (size_t)grow * K + gch * 16;
  int ldst = tid * 16;

  v4f acc[8][4];
  #pragma unroll
  for (int m = 0; m < 8; m++)
    #pragma unroll
    for (int n = 0; n < 4; n++) acc[m][n] = 0.f;

  auto stage = [&](int kt, int buf) {
    const unsigned char* ga = Ab + stago + kt * 64;
    unsigned char* la = lds + buf * 24576 + ldst;
    gl_lds16(ga, la);                                  // A rows [0,64)
    gl_lds16(ga + (size_t)64 * K, la + 4096);          // A rows [64,128)
    gl_lds16(ga + (size_t)128 * K, la + 8192);         // A rows [128,192)
    gl_lds16(ga + (size_t)192 * K, la + 12288);        // A rows [192,256)
    const unsigned char* gb = Bb + stago + kt * 64;
    gl_lds16(gb, la + 16384);                          // B rows [0,64)
    gl_lds16(gb + (size_t)64 * K, la + 20480);         // B rows [64,128)
  };

  int NT = K >> 6;
  stage(0, 0);
  stage(min(1, NT - 1), 1);
  G_VM6(); G_BAR();
  int cur = 0;
  for (int t = 0; t < NT; t++) {
    int kt2 = (t + 2 < NT) ? t + 2 : NT - 1;
    int nxt = cur + 2; if (nxt >= 3) nxt -= 3;
    stage(kt2, nxt);
    const unsigned char* ab = lds + cur * 24576 + arow;
    const unsigned char* bb = lds + cur * 24576 + 16384 + brow;
    i64x2 a[8], b[4];
    #pragma unroll
    for (int m = 0; m < 8; m++) a[m] = *(const i64x2*)(ab + m * 1024 + ck);
    #pragma unroll
    for (int n = 0; n < 4; n++) b[n] = *(const i64x2*)(bb + n * 1024 + ck);
    __builtin_amdgcn_s_setprio(1);
    #pragma unroll
    for (int m = 0; m < 8; m++)
      #pragma unroll
      for (int n = 0; n < 4; n++)
        acc[m][n] = __builtin_amdgcn_mfma_f32_16x16x32_fp8_fp8(a[m].x, b[n].x, acc[m][n], 0, 0, 0);
    #pragma unroll
    for (int m = 0; m < 8; m++)
      #pragma unroll
      for (int n = 0; n < 4; n++)
        acc[m][n] = __builtin_amdgcn_mfma_f32_16x16x32_fp8_fp8(a[m].y, b[n].y, acc[m][n], 0, 0, 0);
    __builtin_amdgcn_s_setprio(0);
    G_VM6(); G_BAR();
    cur++; if (cur == 3) cur = 0;
  }
  G_VM0();

  int chb0 = m0 + wm * 128;          // wave covers 128 channels
  int tb0  = n0 + wn * 64;
  if constexpr (EPI == 1) {
    // fused q/k LayerNorm; wave's 128 channels = two 64-ch (he,s) groups
    unsigned char* out8 = (unsigned char*)outp;
    #pragma unroll
    for (int n = 0; n < 4; n++) {
      int t = tb0 + n * 16 + l15;
      #pragma unroll
      for (int h = 0; h < 2; h++) {
        int ch64 = (chb0 >> 6) + h;
        int he = ch64 / 3, s = ch64 % 3;
        unsigned char* orow = out8 + (size_t)(s * kHE + he) * kNT * 64 + (size_t)t * 64;
        float vv[4][4];
        float s1 = 0.f, s2 = 0.f;
        #pragma unroll
        for (int m4 = 0; m4 < 4; m4++) {
          int m = h * 4 + m4;
          float4 bb = *(const float4*)&bias[chb0 + m * 16 + lq * 4];
          float v0 = acc[m][n][0] * S + bb.x, v1 = acc[m][n][1] * S + bb.y;
          float v2 = acc[m][n][2] * S + bb.z, v3 = acc[m][n][3] * S + bb.w;
          vv[m4][0] = v0; vv[m4][1] = v1; vv[m4][2] = v2; vv[m4][3] = v3;
          s1 += v0 + v1 + v2 + v3;
          s2 += v0 * v0 + v1 * v1 + v2 * v2 + v3 * v3;
        }
        s1 += __shfl_xor(s1, 16); s1 += __shfl_xor(s1, 32);
        s2 += __shfl_xor(s2, 16); s2 += __shfl_xor(s2, 32);
        if (s < 2) {
          const float* wp = s ? ln1w : ln0w;
          const float* bp = s ? ln1b : ln0b;
          float mu = s1 * (1.f / 64.f);
          float inv = rsqrtf(s2 * (1.f / 64.f) - mu * mu + 1e-5f);
          #pragma unroll
          for (int m4 = 0; m4 < 4; m4++) {
            int j = m4 * 16 + lq * 4;
            float4 w4 = *(const float4*)&wp[j];
            float4 b4 = *(const float4*)&bp[j];
            vv[m4][0] = (vv[m4][0] - mu) * inv * w4.x + b4.x;
            vv[m4][1] = (vv[m4][1] - mu) * inv * w4.y + b4.y;
            vv[m4][2] = (vv[m4][2] - mu) * inv * w4.z + b4.z;
            vv[m4][3] = (vv[m4][3] - mu) * inv * w4.w + b4.w;
          }
        }
        unsigned wds[4];
        #pragma unroll
        for (int m4 = 0; m4 < 4; m4++)
          wds[m4] = pk4fp8(vv[m4][0], vv[m4][1], vv[m4][2], vv[m4][3]);
        #pragma unroll
        for (int m4 = 0; m4 < 4; m4++)
          *(unsigned*)(orow + m4 * 16 + lq * 4) = wds[m4];
      }
    }
  } else if constexpr (EPI == 2) {
    unsigned char* out8 = (unsigned char*)outp;
    int b_ = tb0 >> 15;
    #pragma unroll
    for (int m = 0; m < 8; m++) {
      int chb = chb0 + m * 16 + lq * 4;
      float4 bb = *(const float4*)&bias[chb];
      #pragma unroll
      for (int n = 0; n < 4; n++) {
        int t = tb0 + n * 16 + l15;
        int sp = t & (kSP - 1);
        size_t cmb = ((size_t)(b_ * kC + chb) << 15) + sp;
        out8[cmb]           = f2fp8(acc[m][n][0] * S + bb.x);
        out8[cmb + kSP]     = f2fp8(acc[m][n][1] * S + bb.y);
        out8[cmb + 2 * kSP] = f2fp8(acc[m][n][2] * S + bb.z);
        out8[cmb + 3 * kSP] = f2fp8(acc[m][n][3] * S + bb.w);
      }
    }
  } else if constexpr (EPI == 3) {
    // n-outer / m-inner, compute-then-store: line-complete bursts.
    unsigned char* out8 = (unsigned char*)outp;
    #pragma unroll
    for (int n = 0; n < 4; n++) {
      int t = tb0 + n * 16 + l15;
      unsigned char* orow = out8 + (size_t)t * ld_out;
      unsigned wds[8];
      #pragma unroll
      for (int m = 0; m < 8; m++) {
        int chb = chb0 + m * 16 + lq * 4;
        float4 bb = *(const float4*)&bias[chb];
        wds[m] = pk4fp8(gelu_fast(acc[m][n][0] * S + bb.x),
                        gelu_fast(acc[m][n][1] * S + bb.y),
                        gelu_fast(acc[m][n][2] * S + bb.z),
                        gelu_fast(acc[m][n][3] * S + bb.w));
      }
      #pragma unroll
      for (int m = 0; m < 8; m++)
        *(unsigned*)(orow + chb0 + m * 16 + lq * 4) = wds[m];
    }
  } else {  // EPI == 4
    unsigned char* out8 = (unsigned char*)outp;
    int b_ = (t0 + tb0) >> 15;
    #pragma unroll
    for (int m = 0; m < 8; m++) {
      int chb = chb0 + m * 16 + lq * 4;
      float4 bb = *(const float4*)&bias[chb];
      float q0 = 0.f, q1 = 0.f, q2 = 0.f, q3 = 0.f;
      #pragma unroll
      for (int n = 0; n < 4; n++) {
        int tg = t0 + tb0 + n * 16 + l15;
        int sp = tg & (kSP - 1);
        size_t cmb = ((size_t)(b_ * kC + chb) << 15) + sp;
        float v0 = acc[m][n][0] * S + bb.x, v1 = acc[m][n][1] * S + bb.y;
        float v2 = acc[m][n][2] * S + bb.z, v3 = acc[m][n][3] * S + bb.w;
        out8[cmb] = f2fp8(v0); out8[cmb + kSP] = f2fp8(v1);
        out8[cmb + 2 * kSP] = f2fp8(v2); out8[cmb + 3 * kSP] = f2fp8(v3);
        q0 += v0 * v0; q1 += v1 * v1; q2 += v2 * v2; q3 += v3 * v3;
      }
      #pragma unroll
      for (int xm = 1; xm < 16; xm <<= 1) {
        q0 += __shfl_xor(q0, xm); q1 += __shfl_xor(q1, xm);
        q2 += __shfl_xor(q2, xm); q3 += __shfl_xor(q3, xm);
      }
      if (l15 == 0) {
        atomicAdd(&stats[b_ * kC + chb], q0);
        atomicAdd(&stats[b_ * kC + chb + 1], q1);
        atomicAdd(&stats[b_ * kC + chb + 2], q2);
        atomicAdd(&stats[b_ * kC + chb + 3], q3);
      }
    }
  }
}

__global__ __launch_bounds__(256) void k_scale(const float* __restrict__ stats,
    const float* __restrict__ w, float* __restrict__ sc, float invn, float post) {
  int i = blockIdx.x * 256 + threadIdx.x;
  if (i >= kB * kC) return;
  sc[i] = post * rsqrtf(stats[i] * invn + 1e-6f) * w[i % kC];
}

// out = x + gatt*z + gmlp*s3*h   (all channel-major [b][c][sp], z/h fp8)
__global__ __launch_bounds__(256) void k_final(float* __restrict__ out,
    const float* __restrict__ x, const unsigned char* __restrict__ z8,
    const unsigned char* __restrict__ h8, const float* __restrict__ s3,
    const float* __restrict__ ga, const float* __restrict__ gm) {
  size_t e = ((size_t)blockIdx.x * 256 + threadIdx.x) * 4;
  int bc = (int)(e >> 15);
  int c = bc % kC;
  float sa = ga[c], sm = gm[c] * s3[bc];
  float4 v = *(const float4*)(x + e);
  unsigned zu = *(const unsigned*)(z8 + e);
  unsigned hu = *(const unsigned*)(h8 + e);
  v.x += sa * fp82f<0>(zu) + sm * fp82f<0>(hu);
  v.y += sa * fp82f<1>(zu) + sm * fp82f<1>(hu);
  v.z += sa * fp82f<2>(zu) + sm * fp82f<2>(hu);
  v.w += sa * fp82f<3>(zu) + sm * fp82f<3>(hu);
  *(float4*)(out + e) = v;
}

// ----------------------------------------------------------------------------
extern "C" void kernel_launch(void* const* d_in, const int* in_sizes, int n_in,
                              void* d_out, int out_size, void* d_ws, size_t ws_size,
                              hipStream_t stream) {
  (void)in_sizes; (void)n_in;
  const float* x    = (const float*)d_in[0];
  const float* n1w  = (const float*)d_in[1];
  const float* n2w  = (const float*)d_in[2];
  const float* nmw  = (const float*)d_in[3];
  const float* qkvw = (const float*)d_in[4];
  const float* qkvb = (const float*)d_in[5];
  const float* outw = (const float*)d_in[6];
  const float* outb = (const float*)d_in[7];
  const float* qnw  = (const float*)d_in[8];
  const float* qnb  = (const float*)d_in[9];
  const float* knw  = (const float*)d_in[10];
  const float* knb  = (const float*)d_in[11];
  const float* gatt = (const float*)d_in[12];
  const float* gmlp = (const float*)d_in[13];
  const float* f1w  = (const float*)d_in[14];
  const float* f1b  = (const float*)d_in[15];
  const float* f2w  = (const float*)d_in[16];
  const float* f2b  = (const float*)d_in[17];

  size_t off = 0;
  auto alloc = [&](size_t bytes) { size_t o = off; off += (bytes + 255) & ~(size_t)255; return o; };
  size_t o_wq8 = alloc((size_t)2 * kC3 * kC);      // per-batch, sc1-folded, x16
  size_t o_wo8 = alloc((size_t)2 * kC * kC);       // per-batch, sc2-folded, x16
  size_t o_w18 = alloc((size_t)kCF * kC);          // x16
  size_t o_w28 = alloc((size_t)kC * kCF);          // x16
  size_t o_s1  = alloc(kB * kC * 4);
  size_t o_s2  = alloc(kB * kC * 4);
  size_t o_s3  = alloc(kB * kC * 4);
  size_t o_st  = alloc(3 * kB * kC * 4);           // stats1 | stats_o | stats_h
  size_t o_y8  = alloc((size_t)kNT * kC);          // y8 = fp8(x^T): GEMM1 B + fc1 B
  size_t o_qk  = alloc((size_t)kNT * kC3);         // qkv8 planes -> h28 (reuse front)
  size_t o_O8  = alloc((size_t)kNT * kC);          // attention accumulator
  size_t o_z   = alloc((size_t)kNT * kC);          // z fp8 channel-major
  size_t o_hc  = alloc((size_t)kNT * kCF);         // hck fp8 (full, 201 MB)
  if (ws_size < off) {
    hipMemsetAsync(d_out, 0x7F, (size_t)out_size * 4, stream);
    return;
  }
  char* ws = (char*)d_ws;
  unsigned char* wq8 = (unsigned char*)(ws + o_wq8);
  unsigned char* wo8 = (unsigned char*)(ws + o_wo8);
  unsigned char* w18 = (unsigned char*)(ws + o_w18);
  unsigned char* w28 = (unsigned char*)(ws + o_w28);
  float* sc1 = (float*)(ws + o_s1);
  float* sc2 = (float*)(ws + o_s2);
  float* sc3 = (float*)(ws + o_s3);
  float* stats1  = (float*)(ws + o_st);
  float* stats_o = stats1 + kB * kC;
  float* stats_h = stats1 + 2 * kB * kC;
  unsigned char* y8   = (unsigned char*)(ws + o_y8);
  unsigned char* qkv8 = (unsigned char*)(ws + o_qk);
  unsigned char* h28  = (unsigned char*)(ws + o_qk);   // reuse (qkv dead after attn)
  unsigned char* O8   = (unsigned char*)(ws + o_O8);
  unsigned char* z8   = (unsigned char*)(ws + o_z);
  unsigned char* hck  = (unsigned char*)(ws + o_hc);
  float* out = (float*)d_out;

  hipMemsetAsync(ws + o_st, 0, 3 * kB * kC * 4, stream);
  k_rms_t<<<dim3(kSP / 256, kC / 64, kB), 256, 0, stream>>>(x, y8, stats1);
  k_scale<<<6, 256, 0, stream>>>(stats1, n1w, sc1, 1.f / kSP, 1.f);
  k_cvt_w12<<<(2 * kCF * kC / 4 + 255) / 256, 256, 0, stream>>>(
      f1w, kCF * kC / 4, f2w, kC * kCF / 4, w18, w28);
  k_cvt_wscale<<<(2 * kC3 * kC / 4 + 255) / 256, 256, 0, stream>>>(qkvw, sc1, wq8, kC3);
  k_gemm8<1><<<4608, 256, 0, stream>>>(wq8, y8, qkvb, kC, 9, 512, 1,
                                       qkv8, 0, (i64)kC3 * kC, nullptr, 0,
                                       qnw, qnb, knw, knb);
  k_attn<0, 0><<<dim3(1024, kHE), 256, 0, stream>>>(qkv8, O8, nullptr);
  k_attn<1, 1><<<dim3(1024, kHE), 256, 0, stream>>>(qkv8, O8, nullptr);
  k_attn<2, 2><<<dim3(1024, kHE), 256, 0, stream>>>(qkv8, O8, stats_o);
  k_scale<<<6, 256, 0, stream>>>(stats_o, n2w, sc2, 1.f / (9.f * kSP), 1.f / 3.f);
  k_cvt_wscale<<<(2 * kC * kC / 4 + 255) / 256, 256, 0, stream>>>(outw, sc2, wo8, kC);
  k_gemm8<2><<<1536, 256, 0, stream>>>(wo8, O8, outb, kC, 3, 512, 1,
                                       z8, 0, (i64)kC * kC, nullptr, 0,
                                       nullptr, nullptr, nullptr, nullptr);
  k_gemm8<3><<<6144, 256, 0, stream>>>(w18, y8, f1b, kC, 12, 512, 1,
                                       hck, kCF, 0, nullptr, 0,
                                       nullptr, nullptr, nullptr, nullptr);
  k_gemm8<4><<<1536, 256, 0, stream>>>(w28, hck, f2b, kCF, 3, 512, 1,
                                       h28, 0, 0, stats_h, 0,
                                       nullptr, nullptr, nullptr, nullptr);
  k_scale<<<6, 256, 0, stream>>>(stats_h, nmw, sc3, 1.f / kSP, 1.f);
  k_final<<<kNT * kC / 1024, 256, 0, stream>>>(out, x, z8, h28, sc3, gatt, gmlp);
}